// Round 5
// baseline (164.363 us; speedup 1.0000x reference)
//
#include <hip/hip_runtime.h>
#include <stdint.h>

#pragma clang fp contract(off)

#define NMS_B 8
#define NMS_N 4096
#define NMS_NW 64       // 64-bit words per suppression row
#define ROIS 256

typedef unsigned long long u64;
typedef unsigned int u32;

__device__ __forceinline__ u64 rdlane_u64(u64 v, int l) {
    u32 lo = (u32)__builtin_amdgcn_readlane((int)(u32)v, l);
    u32 hi = (u32)__builtin_amdgcn_readlane((int)(u32)(v >> 32), l);
    return ((u64)hi << 32) | lo;
}
__device__ __forceinline__ int lds_slot(int e) { return e + (e >> 2); }  // 4-way max bank aliasing

__device__ __forceinline__ void load_lds16(const u64* g, u64* l) {
    // 16 B per lane, deposited at wave-uniform LDS base + lane*16
    __builtin_amdgcn_global_load_lds(
        (const __attribute__((address_space(1))) void*)g,
        (__attribute__((address_space(3))) void*)l, 16, 0, 0);
}

// ---------------------------------------------------------------------------
// K1a: local bitonic sort of 1024-element chunks (4 chunks/batch, 32 blocks).
// key = (~score_bits)<<32 | GLOBAL idx; all direction bits use global e, so
// the result is bit-identical to the monolithic bitonic after its k=1024
// iteration. 55 of 78 stages run here at 4x parallelism.
// ---------------------------------------------------------------------------
__global__ __launch_bounds__(256) void nms_sort_local(
        const float* __restrict__ in, u64* __restrict__ keyb) {
    __shared__ u64 sm[1280];                   // slot(1023)=1278, 10 KB
    const int b = blockIdx.y, c = blockIdx.x, t = threadIdx.x;
    const int ebase = c * 1024;
    u64 key[4];

    #pragma unroll
    for (int r = 0; r < 4; ++r) {
        int e = ebase + 4 * t + r;
        float s = in[((size_t)b * NMS_N + e) * 5];
        key[r] = ((u64)(~__float_as_uint(s)) << 32) | (u32)e;
    }

    for (int k = 2; k <= 1024; k <<= 1) {
        int j = k >> 1;
        if (j >= 256) {                        // j=256 (k=512), j=512,256 (k=1024)
            #pragma unroll
            for (int r = 0; r < 4; ++r) sm[lds_slot(4 * t + r)] = key[r];
            __syncthreads();
            for (; j >= 256; j >>= 1) {
                for (int el = t; el < 1024; el += 256) {
                    int p = el ^ j;
                    if (p > el) {
                        u64 a = sm[lds_slot(el)], cc = sm[lds_slot(p)];
                        bool up = (((ebase + el) & k) == 0);
                        if ((a > cc) == up) { sm[lds_slot(el)] = cc; sm[lds_slot(p)] = a; }
                    }
                }
                __syncthreads();
            }
            #pragma unroll
            for (int r = 0; r < 4; ++r) key[r] = sm[lds_slot(4 * t + r)];
        }
        for (; j >= 4; j >>= 1) {              // cross-lane via shfl_xor
            int d = j >> 2;
            #pragma unroll
            for (int r = 0; r < 4; ++r) {
                int e = ebase + 4 * t + r;
                u64 mine = key[r];
                u64 part = __shfl_xor(mine, d, 64);
                bool up = ((e & k) == 0);
                bool lower = ((e & j) == 0);
                u64 mn = (mine < part) ? mine : part;
                u64 mx = (mine < part) ? part : mine;
                key[r] = (up == lower) ? mn : mx;
            }
        }
        for (; j >= 1; j >>= 1) {              // j in {2,1}: in-thread
            #pragma unroll
            for (int r = 0; r < 4; ++r) {
                int pr = r | j;
                if (((r & j) == 0) && pr < 4) {
                    int e = ebase + 4 * t + r;
                    bool up = ((e & k) == 0);
                    u64 a = key[r], cc = key[pr];
                    if ((a > cc) == up) { key[r] = cc; key[pr] = a; }
                }
            }
        }
    }

    #pragma unroll
    for (int r = 0; r < 4; ++r)
        keyb[(size_t)b * NMS_N + ebase + 4 * t + r] = key[r];
}

// ---------------------------------------------------------------------------
// K1b: merge stages k=2048,4096 (23 stages, 1 block/batch), then epilogue:
// sorted idx + corners (floor(w/2) exactly per reference) + HALF-areas
// (exact: areas are small even integers).
// ---------------------------------------------------------------------------
__global__ __launch_bounds__(1024) void nms_sort_merge(
        const float* __restrict__ in, const u64* __restrict__ keyb,
        u32* __restrict__ sortedIdx, float4* __restrict__ crn,
        float* __restrict__ ha) {
    __shared__ u64 sm[5120];                   // slot(4095)=5118, 41 KB
    const int b = blockIdx.x, t = threadIdx.x;
    u64 key[4];

    #pragma unroll
    for (int r = 0; r < 4; ++r)
        key[r] = keyb[(size_t)b * NMS_N + 4 * t + r];

    for (int k = 2048; k <= 4096; k <<= 1) {
        int j = k >> 1;
        if (j >= 256) {
            #pragma unroll
            for (int r = 0; r < 4; ++r) sm[lds_slot(4 * t + r)] = key[r];
            __syncthreads();
            for (; j >= 256; j >>= 1) {
                for (int e = t; e < NMS_N; e += 1024) {
                    int p = e ^ j;
                    if (p > e) {
                        u64 a = sm[lds_slot(e)], cc = sm[lds_slot(p)];
                        bool up = ((e & k) == 0);
                        if ((a > cc) == up) { sm[lds_slot(e)] = cc; sm[lds_slot(p)] = a; }
                    }
                }
                __syncthreads();
            }
            #pragma unroll
            for (int r = 0; r < 4; ++r) key[r] = sm[lds_slot(4 * t + r)];
        }
        for (; j >= 4; j >>= 1) {
            int d = j >> 2;
            #pragma unroll
            for (int r = 0; r < 4; ++r) {
                int e = 4 * t + r;
                u64 mine = key[r];
                u64 part = __shfl_xor(mine, d, 64);
                bool up = ((e & k) == 0);
                bool lower = ((e & j) == 0);
                u64 mn = (mine < part) ? mine : part;
                u64 mx = (mine < part) ? part : mine;
                key[r] = (up == lower) ? mn : mx;
            }
        }
        for (; j >= 1; j >>= 1) {
            #pragma unroll
            for (int r = 0; r < 4; ++r) {
                int pr = r | j;
                if (((r & j) == 0) && pr < 4) {
                    int e = 4 * t + r;
                    bool up = ((e & k) == 0);
                    u64 a = key[r], cc = key[pr];
                    if ((a > cc) == up) { key[r] = cc; key[pr] = a; }
                }
            }
        }
    }

    #pragma unroll
    for (int r = 0; r < 4; ++r) {
        int e = 4 * t + r;
        u32 orig = (u32)key[r];
        const float* bp = in + ((size_t)b * NMS_N + orig) * 5;
        float x = bp[1], y = bp[2], w = bp[3], h = bp[4];
        float ws_ = floorf(w * 0.5f);
        float hs_ = floorf(h * 0.5f);
        float X1 = x - ws_, Y1 = y - hs_, X2 = x + ws_, Y2 = y + hs_;
        size_t g = (size_t)b * NMS_N + e;
        sortedIdx[g] = orig;
        crn[g] = make_float4(X1, Y1, X2, Y2);
        ha[g] = 0.5f * ((X2 - X1) * (Y2 - Y1));   // exact: area is a small int
    }
}

// ---------------------------------------------------------------------------
// K2: suppression bitmask, ballot orientation, EQUAL-WORK trapezoid grid.
// (unchanged from R3/R4 — correct, ~15-20 us)
// ---------------------------------------------------------------------------
__global__ __launch_bounds__(256) void nms_mask(
        const float4* __restrict__ crn, const float* __restrict__ ha,
        u64* __restrict__ mask) {
    const int b = blockIdx.y;
    const int u = blockIdx.x * 4 + (threadIdx.x >> 6);   // unit id, 0..1055
    const int lane = threadIdx.x & 63;

    int wp = (int)sqrtf((float)u);
    while (wp * (wp + 1) > u) --wp;
    while ((wp + 1) * (wp + 2) <= u) ++wp;
    const int rowblk = u - wp * (wp + 1);                // 0..2*wp+1

    const size_t base = (size_t)b * NMS_N;
    const int c0 = wp * 128 + lane;
    float4 c0c = crn[base + c0];
    float4 c1c = crn[base + c0 + 64];
    float h0 = ha[base + c0];
    float h1 = ha[base + c0 + 64];

    const int rowbase = __builtin_amdgcn_readfirstlane(rowblk * 64);
    const float4* rowc = crn + base + rowbase;
    const float* rowh = ha + base + rowbase;

    u64 w0 = 0, w1 = 0;
    for (int rg = 0; rg < 64; rg += 8) {
        float fx1[8], fy1[8], fx2[8], fy2[8], fha[8];
        #pragma unroll
        for (int q = 0; q < 8; ++q) {                    // uniform -> s_load
            float4 rc = rowc[rg + q];
            fx1[q] = rc.x; fy1[q] = rc.y; fx2[q] = rc.z; fy2[q] = rc.w;
            fha[q] = rowh[rg + q];
        }
        #pragma unroll
        for (int q = 0; q < 8; ++q) {
            float iw0 = fmaxf(fminf(fx2[q], c0c.z) - fmaxf(fx1[q], c0c.x), 0.0f);
            float ih0 = fmaxf(fminf(fy2[q], c0c.w) - fmaxf(fy1[q], c0c.y), 0.0f);
            float in0 = iw0 * ih0;
            bool p0 = in0 > fmaf(-0.5f, in0, fha[q] + h0);

            float iw1 = fmaxf(fminf(fx2[q], c1c.z) - fmaxf(fx1[q], c1c.x), 0.0f);
            float ih1 = fmaxf(fminf(fy2[q], c1c.w) - fmaxf(fy1[q], c1c.y), 0.0f);
            float in1 = iw1 * ih1;
            bool p1 = in1 > fmaf(-0.5f, in1, fha[q] + h1);

            u64 b0 = __ballot(p0);
            u64 b1 = __ballot(p1);
            if (lane == rg + q) { w0 = b0; w1 = b1; }
        }
    }

    ulonglong2 v; v.x = w0; v.y = w1;
    *(ulonglong2*)&mask[(base + rowbase + lane) * NMS_NW + wp * 2] = v;
}

// ---------------------------------------------------------------------------
// K3 v3: one wave per batch, LDS-pipelined greedy scan.
// Per-lane state S = suppression word of window `lane` (4096 bits total).
// Window W's full 64 rows x 512 B of mask are prefetched into LDS (via
// global_load_lds, double-buffered) DURING window W-1's serial scan, so the
// L3 latency is off the critical path. Serial ctz loop uses the prefetched
// diag (lane r = word W of row 64W+r; self-bit cleared explicitly). Kept
// rows' full mask rows are OR'd into S from LDS (4-wide ds_read batches).
// Kept list lives in registers: lane W accumulates its window's kept bits;
// epilogue = shfl prefix-scan + per-lane scattered writes. Garbage in
// below-diagonal (unwritten) mask words only ever reaches S-lanes < current
// window, which are never read again.
// ---------------------------------------------------------------------------
__global__ __launch_bounds__(64, 1) void nms_scan(
        const float* __restrict__ in, const u64* __restrict__ mask,
        const u32* __restrict__ sortedIdx, float* __restrict__ outp) {
    const int b = blockIdx.x, lane = threadIdx.x;
    const u64* M = mask + (size_t)b * NMS_N * NMS_NW;
    __shared__ u64 win[2][NMS_N];              // 2 x 32 KB = 64 KB

    u64 S = 0, mykept = 0;
    int count = 0;

    // issue window-0 prefetch (32 x 1 KB) + diag0
    for (int rp = 0; rp < 32; ++rp)
        load_lds16(M + (size_t)rp * 2 * NMS_NW + lane * 2, &win[0][rp * 128]);
    u64 diag = M[(size_t)lane * NMS_NW];       // word 0 of row `lane`

    for (int W = 0; W < 64; ++W) {
        const int buf = W & 1;
        __builtin_amdgcn_s_waitcnt(0);         // win[buf] + diag arrived
        __syncthreads();

        u64 nextdiag = 0;
        if (W + 1 < 64) {                      // prefetch W+1 while scanning W
            const u64* nb = M + (size_t)(W + 1) * 64 * NMS_NW;
            for (int rp = 0; rp < 32; ++rp)
                load_lds16(nb + (size_t)rp * 2 * NMS_NW + lane * 2,
                           &win[1 - buf][rp * 128]);
            nextdiag = M[(size_t)((W + 1) * 64 + lane) * NMS_NW + (W + 1)];
        }

        // serial scalar ctz-skip scan of this window
        u64 avail = ~rdlane_u64(S, W);
        u64 km = 0;
        while (avail != 0 && count < ROIS) {
            int r = __builtin_ctzll(avail);
            u64 d = rdlane_u64(diag, r);
            km |= (1ULL << r);
            ++count;
            avail &= ~(d | (1ULL << r));
        }
        if (lane == W) mykept = km;
        if (count >= ROIS) break;

        // flush kept rows' full mask rows (LDS) into S, 4-wide batches
        while (km != 0) {
            u64 t0, t1 = 0, t2 = 0, t3 = 0;
            int r0 = __builtin_ctzll(km); km &= km - 1;
            t0 = win[buf][r0 * 64 + lane];
            if (km) { int r1 = __builtin_ctzll(km); km &= km - 1; t1 = win[buf][r1 * 64 + lane]; }
            if (km) { int r2 = __builtin_ctzll(km); km &= km - 1; t2 = win[buf][r2 * 64 + lane]; }
            if (km) { int r3 = __builtin_ctzll(km); km &= km - 1; t3 = win[buf][r3 * 64 + lane]; }
            S |= (t0 | t1) | (t2 | t3);
        }
        diag = nextdiag;
    }

    // epilogue: register kept-list -> output (count==256 for this workload)
    int cnt = (int)__popcll(mykept);
    int pre = cnt;
    #pragma unroll
    for (int d = 1; d < 64; d <<= 1) {
        int tsum = __shfl_up(pre, d, 64);
        if (lane >= d) pre += tsum;
    }
    pre -= cnt;                                // exclusive prefix over lanes
    u64 bits = mykept;
    int slot = pre;
    while (bits != 0) {
        int r = __builtin_ctzll(bits); bits &= bits - 1;
        if (slot < ROIS) {
            int pos = lane * 64 + r;
            int orig = (int)sortedIdx[(size_t)b * NMS_N + pos];
            const float* bp = in + ((size_t)b * NMS_N + orig) * 5;
            float4 o = make_float4(bp[1], bp[2], bp[3], bp[4]);
            ((float4*)outp)[(size_t)b * ROIS + slot] = o;
        }
        ++slot;
    }
}

extern "C" void kernel_launch(void* const* d_in, const int* in_sizes, int n_in,
                              void* d_out, int out_size, void* d_ws, size_t ws_size,
                              hipStream_t stream) {
    const float* in = (const float*)d_in[0];
    float* out = (float*)d_out;
    char* ws = (char*)d_ws;

    u64* mask = (u64*)ws;                                          // 16 MB
    size_t off = (size_t)NMS_B * NMS_N * NMS_NW * sizeof(u64);
    u32* sortedIdx = (u32*)(ws + off); off += (size_t)NMS_B * NMS_N * 4;
    float4* crn = (float4*)(ws + off); off += (size_t)NMS_B * NMS_N * 16;
    float* ha = (float*)(ws + off);    off += (size_t)NMS_B * NMS_N * 4;
    u64* keyb = (u64*)(ws + off);      off += (size_t)NMS_B * NMS_N * 8;

    nms_sort_local<<<dim3(4, NMS_B), 256, 0, stream>>>(in, keyb);
    nms_sort_merge<<<NMS_B, 1024, 0, stream>>>(in, keyb, sortedIdx, crn, ha);
    nms_mask<<<dim3(264, NMS_B), 256, 0, stream>>>(crn, ha, mask);
    nms_scan<<<NMS_B, 64, 0, stream>>>(in, mask, sortedIdx, out);
}